// Round 8
// baseline (133.651 us; speedup 1.0000x reference)
//
#include <hip/hip_runtime.h>
#include <math.h>

typedef __attribute__((ext_vector_type(4))) int i32x4;
typedef __attribute__((ext_vector_type(2))) int i32x2;
typedef __attribute__((ext_vector_type(4))) float f32x4;

#define GLOAD_LDS16(g, l)                                          \
  __builtin_amdgcn_global_load_lds(                                \
      (const __attribute__((address_space(1))) void*)(g),          \
      (__attribute__((address_space(3))) void*)(l), 16, 0, 0)

// ---------------- weight quantization (merged: W1 blocks 0-255, W2 blocks 256-511) ----------
__global__ void kWabs(const float* __restrict__ w1, const float* __restrict__ w2,
                      double* __restrict__ part) {
  const bool second = blockIdx.x >= 256;
  const float* w = second ? w2 : w1;
  const int n = second ? 262144 : 524288;
  int t = (blockIdx.x & 255) * 256 + threadIdx.x;
  double s = 0.0;
  for (int i = t; i < n; i += 65536) s += (double)fabsf(w[i]);
#pragma unroll
  for (int m = 32; m >= 1; m >>= 1) s += __shfl_xor(s, m);
  __shared__ double sd[4];
  int lane = threadIdx.x & 63, wid = threadIdx.x >> 6;
  if (lane == 0) sd[wid] = s;
  __syncthreads();
  if (threadIdx.x == 0) part[blockIdx.x] = (sd[0] + sd[1]) + (sd[2] + sd[3]);
}

__global__ void kWfin(const double* __restrict__ part, float* __restrict__ wsv) {
  const double* p = part + blockIdx.x * 256;
  const double n = (blockIdx.x == 0) ? 524288.0 : 262144.0;
  double s = p[threadIdx.x];
#pragma unroll
  for (int m = 32; m >= 1; m >>= 1) s += __shfl_xor(s, m);
  __shared__ double sd[4];
  int lane = threadIdx.x & 63, wid = threadIdx.x >> 6;
  if (lane == 0) sd[wid] = s;
  __syncthreads();
  if (threadIdx.x == 0) {
    double tot = (sd[0] + sd[1]) + (sd[2] + sd[3]);
    wsv[blockIdx.x] = fmaxf((float)(tot / n), 1e-5f);  // = 1/scale_w
  }
}

__global__ void kWq(const float* __restrict__ w1, const float* __restrict__ w2,
                    const float* __restrict__ wsv,
                    char* __restrict__ wq1, char* __restrict__ wq2) {
  const bool second = blockIdx.x >= 2048;
  const float* w = second ? w2 : w1;
  char* wq = second ? wq2 : wq1;
  const float scale = 1.0f / wsv[second ? 1 : 0];
  int i = (second ? blockIdx.x - 2048 : blockIdx.x) * 256 + threadIdx.x;
  float q = fminf(fmaxf(rintf(w[i] * scale), -1.0f), 1.0f);
  wq[i] = (char)(int)q;
}

// ---------------- input RMSNorm + absmax quant: 4 rows/wave, software-pipelined ----------
// Wave processes rows {base, base+8192, base+16384, base+24576}; loads of row r+1
// are issued BEFORE the reduce/quant of row r so HBM stays busy through compute.
__global__ __launch_bounds__(512) void kQ1(
    const float* __restrict__ prior, const float* __restrict__ evid,
    char* __restrict__ Xq, float* __restrict__ rAct) {
  const int w = threadIdx.x >> 6;
  const int l = threadIdx.x & 63;
  size_t row = (size_t)blockIdx.x * 8 + w;  // [0, 8192)
  f32x4 a0, a1, a2, a3;
  {
    const f32x4* pp = (const f32x4*)(prior + row * 512) + l * 2;
    const f32x4* pe = (const f32x4*)(evid + row * 512) + l * 2;
    a0 = pp[0]; a1 = pp[1]; a2 = pe[0]; a3 = pe[1];
  }
#pragma unroll
  for (int it = 0; it < 4; ++it) {
    f32x4 b0, b1, b2, b3;
    if (it < 3) {  // prefetch next row (in flight during reduce/quant below)
      const f32x4* pp = (const f32x4*)(prior + (row + 8192) * 512) + l * 2;
      const f32x4* pe = (const f32x4*)(evid + (row + 8192) * 512) + l * 2;
      b0 = pp[0]; b1 = pp[1]; b2 = pe[0]; b3 = pe[1];
    }
    float ss = 0.f, mx = 0.f;
    f32x4 x[4] = {a0, a1, a2, a3};
#pragma unroll
    for (int v = 0; v < 4; ++v)
#pragma unroll
      for (int i = 0; i < 4; ++i) { float f = x[v][i]; ss += f * f; mx = fmaxf(mx, fabsf(f)); }
#pragma unroll
    for (int m = 32; m >= 1; m >>= 1) { ss += __shfl_xor(ss, m); mx = fmaxf(mx, __shfl_xor(mx, m)); }
    const float inv = 1.0f / sqrtf(ss * (1.0f / 1024.0f) + 1e-6f);
    const float amax = fmaxf(mx * inv, 1e-5f);
    const float s = 127.0f / amax;
    int pk[4];
#pragma unroll
    for (int v = 0; v < 4; ++v) {
      int p = 0;
#pragma unroll
      for (int i = 0; i < 4; ++i) {
        int qi = (int)fminf(fmaxf(rintf(x[v][i] * inv * s), -128.0f), 127.0f);
        p |= (qi & 255) << (8 * i);
      }
      pk[v] = p;
    }
    char* dst = Xq + row * 1024 + l * 8;
    *(i32x2*)dst = (i32x2){pk[0], pk[1]};          // prior half
    *(i32x2*)(dst + 512) = (i32x2){pk[2], pk[3]};  // evid half
    if (l == 0) rAct[row] = amax / 127.0f;
    if (it < 3) { a0 = b0; a1 = b1; a2 = b2; a3 = b3; row += 8192; }
  }
}

// ---------------- fused BitLinear GEMM, i8 MFMA, 64 x 512 tile (full N) ----------------
// Double-buffered 2-phase: STAGE(next) issued BEFORE ds_read+MFMA(cur);
// one __syncthreads per K-step (implicit vmcnt(0) drain after MFMA cover).
// L1: +ReLU +row-RMSNorm +requant -> i8 X2q, r2
// L2: +sigmoid, *prior -> unnormalized posterior + per-block col sums
template <int KDIM, bool L1>
__global__ __launch_bounds__(512, 4) void kGemm(
    const char* __restrict__ Xq, const char* __restrict__ Wq,
    const float* __restrict__ biasG, const float* __restrict__ rAct,
    const float* __restrict__ wS,
    char* __restrict__ XqOut, float* __restrict__ rActOut,
    const float* __restrict__ prior, float* __restrict__ outUn,
    float* __restrict__ partG) {
  struct Stage { char A[4096]; char B[32768]; };
  __shared__ __align__(16) union {
    Stage st[2];                                     // 73,728 B double buffer
    struct { float sq[64][8]; float mx[64][8]; } ep; // L1 cross-wave row reduce (overlays st[0])
  } u;
  __shared__ float rowR[64];
  __shared__ float biasS[512];
  __shared__ float normPart[512];

  const int tid = threadIdx.x;
  const int lane = tid & 63;
  const int wn = tid >> 6;   // wave -> 64-col strip (0..7)
  const int lr = lane & 15;
  const int kg = lane >> 4;  // 0..3
  const size_t row0 = (size_t)blockIdx.x * 64;

  if (tid < 64) rowR[tid] = rAct[row0 + tid];
  biasS[tid] = biasG[tid];

  i32x4 acc[4][4];
#pragma unroll
  for (int a = 0; a < 4; ++a)
#pragma unroll
    for (int b = 0; b < 4; ++b) acc[a][b] = (i32x4){0, 0, 0, 0};

  const int lrow = lane >> 2;       // row within a 16-row chunk
  const int lkb = (lane & 3) * 16;  // 16B k-slice within a 64B row

  // wave-invariant global bases (advance by k0 per step)
  const char* gA = Xq + (row0 + (wn & 3) * 16 + lrow) * (size_t)KDIM + lkb;
  const char* gB[4];
#pragma unroll
  for (int r = 0; r < 4; ++r)
    gB[r] = Wq + ((wn * 4 + r) * 16 + lrow) * (size_t)KDIM + lkb;

#define STAGE(b, k0)                                                   \
  do {                                                                 \
    if (wn < 4) GLOAD_LDS16(gA + (k0), &u.st[b].A[(wn & 3) * 1024]);   \
    _Pragma("unroll")                                                  \
    for (int r = 0; r < 4; ++r)                                        \
      GLOAD_LDS16(gB[r] + (k0), &u.st[b].B[(wn * 4 + r) * 1024]);      \
  } while (0)

  constexpr int NT = KDIM / 64;
  STAGE(0, 0);
  __syncthreads();  // vmcnt(0) drain: buf0 ready

#pragma unroll 2
  for (int kt = 0; kt < NT; ++kt) {
    const int cur = kt & 1;
    if (kt + 1 < NT) STAGE(cur ^ 1, (kt + 1) * 64);  // prefetch BEFORE compute
    i32x4 af[4];
#pragma unroll
    for (int fm = 0; fm < 4; ++fm)
      af[fm] = *(const i32x4*)&u.st[cur].A[(fm * 16 + lr) * 64 + kg * 16];
#pragma unroll
    for (int fn = 0; fn < 4; ++fn) {
      i32x4 bf = *(const i32x4*)&u.st[cur].B[(wn * 64 + fn * 16 + lr) * 64 + kg * 16];
#pragma unroll
      for (int fm = 0; fm < 4; ++fm)
        acc[fm][fn] = __builtin_amdgcn_mfma_i32_16x16x64_i8(af[fm], bf, acc[fm][fn], 0, 0, 0);
    }
    __syncthreads();  // drains vmcnt(0): prefetched buf ready; cur safe to overwrite
  }
#undef STAGE

  // ---- epilogue: acc element j -> row fm*16+kg*4+j, col wn*64+fn*16+lr
  const float wsv_ = wS[0];

  if constexpr (L1) {
    f32x4 fa[4][4];
#pragma unroll
    for (int fm = 0; fm < 4; ++fm) {
      float sc[4];
#pragma unroll
      for (int j = 0; j < 4; ++j) sc[j] = rowR[fm * 16 + kg * 4 + j] * wsv_;
#pragma unroll
      for (int fn = 0; fn < 4; ++fn) {
        const float bb = biasS[wn * 64 + fn * 16 + lr];
#pragma unroll
        for (int j = 0; j < 4; ++j)
          fa[fm][fn][j] = fmaxf((float)acc[fm][fn][j] * sc[j] + bb, 0.0f);
      }
    }
    // per-row sumsq/absmax: 4 local cols -> 16-lane shfl -> cross-wave LDS
#pragma unroll
    for (int fm = 0; fm < 4; ++fm)
#pragma unroll
      for (int j = 0; j < 4; ++j) {
        float ss = 0.f, mx = 0.f;
#pragma unroll
        for (int fn = 0; fn < 4; ++fn) { float h = fa[fm][fn][j]; ss += h * h; mx = fmaxf(mx, h); }
#pragma unroll
        for (int m = 8; m >= 1; m >>= 1) { ss += __shfl_xor(ss, m); mx = fmaxf(mx, __shfl_xor(mx, m)); }
        if (lr == 0) {
          int rl = fm * 16 + kg * 4 + j;
          u.ep.sq[rl][wn] = ss;
          u.ep.mx[rl][wn] = mx;
        }
      }
    __syncthreads();
#pragma unroll
    for (int fm = 0; fm < 4; ++fm)
#pragma unroll
      for (int j = 0; j < 4; ++j) {
        const int rl = fm * 16 + kg * 4 + j;
        float sst = 0.f, mxt = 0.f;
#pragma unroll
        for (int w = 0; w < 8; ++w) {
          sst += u.ep.sq[rl][w];
          mxt = fmaxf(mxt, u.ep.mx[rl][w]);
        }
        float inv = 1.0f / sqrtf(sst * (1.0f / 512.0f) + 1e-6f);
        float amax = fmaxf(mxt * inv, 1e-5f);
        float s = 127.0f / amax;
        if (lr == 0 && wn == 0) rActOut[row0 + rl] = amax / 127.0f;
#pragma unroll
        for (int fn = 0; fn < 4; ++fn) {
          float xn = fa[fm][fn][j] * inv;
          int qi = (int)fminf(fmaxf(rintf(xn * s), -128.0f), 127.0f);
          XqOut[(row0 + rl) * 512 + wn * 64 + fn * 16 + lr] = (char)qi;
        }
      }
  } else {
    float colsum[4] = {0.f, 0.f, 0.f, 0.f};
#pragma unroll
    for (int fm = 0; fm < 4; ++fm) {
      float sc[4];
#pragma unroll
      for (int j = 0; j < 4; ++j) sc[j] = rowR[fm * 16 + kg * 4 + j] * wsv_;
#pragma unroll
      for (int fn = 0; fn < 4; ++fn) {
        const int col = wn * 64 + fn * 16 + lr;
        const float bb = biasS[col];
#pragma unroll
        for (int j = 0; j < 4; ++j) {
          const size_t rg = row0 + fm * 16 + kg * 4 + j;
          float v = (float)acc[fm][fn][j] * sc[j] + bb;
          float like = 1.0f / (1.0f + expf(-v));
          float un = prior[rg * 512 + col] * like;
          outUn[rg * 512 + col] = un;
          colsum[fn] += un;
        }
      }
    }
#pragma unroll
    for (int fn = 0; fn < 4; ++fn) {  // reduce over the wave's 4 kg row-groups
      colsum[fn] += __shfl_xor(colsum[fn], 16);
      colsum[fn] += __shfl_xor(colsum[fn], 32);
    }
    if (lane < 16) {  // one wave per column strip: plain store, deterministic
#pragma unroll
      for (int fn = 0; fn < 4; ++fn) normPart[wn * 64 + fn * 16 + lane] = colsum[fn];
    }
    __syncthreads();
    partG[(size_t)blockIdx.x * 512 + tid] = normPart[tid];
  }
}

// ---------------- normalization over S ----------------
__global__ void kNorm1(const float* __restrict__ partG, float* __restrict__ normA) {
  const int b = blockIdx.x, f = threadIdx.x;  // 32 x 512; 16 GEMM2 blocks per batch
  float s = 0.f;
#pragma unroll
  for (int i = 0; i < 16; ++i) s += partG[(size_t)(b * 16 + i) * 512 + f];
  normA[b * 512 + f] = fmaxf(s, 1e-10f);
}

__global__ void kNorm2(float* __restrict__ out, const float* __restrict__ normA) {
  const size_t i4 = (size_t)blockIdx.x * blockDim.x + threadIdx.x;  // float4 index
  f32x4 v = ((const f32x4*)out)[i4];
  const int f4 = (int)(i4 & 127);
  const int b = (int)(i4 >> 17);
  f32x4 n = ((const f32x4*)normA)[b * 128 + f4];
  v[0] /= n[0]; v[1] /= n[1]; v[2] /= n[2]; v[3] /= n[3];
  ((f32x4*)out)[i4] = v;
}

// ---------------- launcher ----------------
extern "C" void kernel_launch(void* const* d_in, const int* in_sizes, int n_in,
                              void* d_out, int out_size, void* d_ws, size_t ws_size,
                              hipStream_t stream) {
  const float* evid  = (const float*)d_in[0];   // [32,1024,512]
  const float* prior = (const float*)d_in[1];   // [32,1024,512]
  const float* W1    = (const float*)d_in[2];   // [512,1024]
  const float* b1    = (const float*)d_in[3];   // [512]
  const float* W2    = (const float*)d_in[4];   // [512,512]
  const float* b2    = (const float*)d_in[5];   // [512]
  float* out = (float*)d_out;

  char* ws = (char*)d_ws;
  char*   X2q   = ws;                              // 16,777,216 B (i8 [32768][512])
  char*   W1q   = ws + 16777216;                   //    524,288 B
  char*   W2q   = ws + 17301504;                   //    262,144 B
  float*  r1    = (float*)(ws + 17563648);         //    131,072 B
  float*  r2    = (float*)(ws + 17694720);         //    131,072 B
  double* part  = (double*)(ws + 17825792);        //      4,096 B
  float*  wsv   = (float*)(ws + 17829888);         //        256 B
  float*  partG = (float*)(ws + 17830144);         //  1,048,576 B
  float*  normA = (float*)(ws + 18878720);         //     65,536 B (total ~18.9 MB)

  // X1q (i8 [32768][1024] = 33.5 MB) lives in d_out (67 MB); dead before GEMM2 writes.
  char* X1q = (char*)d_out;

  kWabs<<<512, 256, 0, stream>>>(W1, W2, part);
  kWfin<<<2, 256, 0, stream>>>(part, wsv);
  kWq<<<3072, 256, 0, stream>>>(W1, W2, wsv, W1q, W2q);
  kQ1<<<1024, 512, 0, stream>>>(prior, evid, X1q, r1);
  kGemm<1024, true><<<512, 512, 0, stream>>>(X1q, W1q, b1, r1, wsv + 0,
                                             X2q, r2, nullptr, nullptr, nullptr);
  kGemm<512, false><<<512, 512, 0, stream>>>(X2q, W2q, b2, r2, wsv + 1,
                                             nullptr, nullptr, prior, out, partG);
  kNorm1<<<32, 512, 0, stream>>>(partG, normA);
  kNorm2<<<16384, 256, 0, stream>>>(out, normA);
}